// Round 1
// baseline (110.670 us; speedup 1.0000x reference)
//
#include <hip/hip_runtime.h>
#include <hip/hip_bf16.h>
#include <math.h>

// Problem: B=128, D=64.
// ref:
//   c_vec[b,c] = mean_{h,w} x[b,c,h,w]
//   h_vec[b,w] = mean_{c,h} x[b,c,h,w]
//   w_vec[b,h] = mean_{c,w} x[b,c,h,w]
//   fc = sigmoid(einsum('ioj,bj->bio', Wc, c_vec))   [b,i,o]
//   fh = sigmoid(einsum('ioj,bj->bio', Wh, h_vec))
//   fw = sigmoid(einsum('ioj,bj->bio', Ww, w_vec))
//   LR[b,c,p,q] = sum_i fc[b,i,c]*fh[b,i,p]*fw[b,i,q]

#define NB 128
#define ND 64

// ---------------------------------------------------------------------------
// Kernel 1: fused triple pooling. Grid 512 = (b, cblk of 16 c). Transposed
// outputs vecT[j][b] so stage 2 can stage them conflict-free.
// ---------------------------------------------------------------------------
__global__ __launch_bounds__(256) void pool_kernel(const float* __restrict__ x,
                                                   float* __restrict__ cvecT,  // [64][128] per-c
                                                   float* __restrict__ hvecT,  // [64][128] per-w (ref h_vec)
                                                   float* __restrict__ wvecT)  // [64][128] per-h (ref w_vec)
{
    const int blk  = blockIdx.x;
    const int b    = blk >> 2;
    const int cblk = blk & 3;
    const int t    = threadIdx.x;
    const int wv   = t >> 6;    // wave 0..3
    const int l    = t & 63;    // lane
    const int lg   = l >> 4;    // 0..3
    const int lw   = l & 15;    // w-group

    __shared__ float cpart[16][4];
    __shared__ float hsum_l[64];    // per-h sums -> w_vec
    __shared__ float wpart[4][64];  // per-w per-wave partial -> h_vec

    const float* xb = x + (size_t)b * 262144 + (size_t)cblk * 16 * 4096;

    float acc_h[4] = {0.f, 0.f, 0.f, 0.f};  // per-h partials (h = wv*16+4k+lg)
    float acc_w[4] = {0.f, 0.f, 0.f, 0.f};  // per-w partials (w = 4*lw+m)

    for (int cc = 0; cc < 16; ++cc) {
        const float* xc = xb + cc * 4096 + wv * 1024 + 4 * l;
        float cs = 0.f;
#pragma unroll
        for (int k = 0; k < 4; ++k) {
            float4 v = *reinterpret_cast<const float4*>(xc + k * 256);
            float s = (v.x + v.y) + (v.z + v.w);
            cs += s;
            acc_h[k] += s;
            acc_w[0] += v.x; acc_w[1] += v.y; acc_w[2] += v.z; acc_w[3] += v.w;
        }
        // full-wave reduce for this c
#pragma unroll
        for (int off = 32; off >= 1; off >>= 1)
            cs += __shfl_xor(cs, off, 64);
        if (l == 0) cpart[cc][wv] = cs;
    }
    // reduce acc_h over the 16 lanes sharing lg (xor 1,2,4,8)
#pragma unroll
    for (int k = 0; k < 4; ++k) {
        float v = acc_h[k];
        v += __shfl_xor(v, 1, 64);
        v += __shfl_xor(v, 2, 64);
        v += __shfl_xor(v, 4, 64);
        v += __shfl_xor(v, 8, 64);
        if (lw == 0) hsum_l[wv * 16 + k * 4 + lg] = v;   // unique h per (wv,k,lg)
    }
    // reduce acc_w over the 4 lanes sharing lw (xor 16,32)
#pragma unroll
    for (int m = 0; m < 4; ++m) {
        float v = acc_w[m];
        v += __shfl_xor(v, 16, 64);
        v += __shfl_xor(v, 32, 64);
        if (lg == 0) wpart[wv][lw * 4 + m] = v;          // w = 4*lw+m
    }
    __syncthreads();

    const float scale = 1.f / 4096.f;
    if (t < 16) {
        float s = cpart[t][0] + cpart[t][1] + cpart[t][2] + cpart[t][3];
        cvecT[(cblk * 16 + t) * NB + b] = s * scale;     // exclusive -> direct store
    }
    if (t < 64) {
        atomicAdd(&wvecT[t * NB + b], hsum_l[t] * scale);                 // per-h
        float ws = wpart[0][t] + wpart[1][t] + wpart[2][t] + wpart[3][t]; // per-w
        atomicAdd(&hvecT[t * NB + b], ws * scale);
    }
}

// ---------------------------------------------------------------------------
// Kernel 2: f{c,h,w}[b,i,o] = sigmoid(sum_j W[i,o,j] * vec[b,j]).
// Grid 192 = (branch, i). W[i] transposed into LDS; vecT staged as-is.
// ---------------------------------------------------------------------------
__global__ __launch_bounds__(256) void fvec_kernel(const float* __restrict__ Wc,
                                                   const float* __restrict__ Wh,
                                                   const float* __restrict__ Ww,
                                                   const float* __restrict__ cvecT,
                                                   const float* __restrict__ hvecT,
                                                   const float* __restrict__ wvecT,
                                                   float* __restrict__ fc,
                                                   float* __restrict__ fh,
                                                   float* __restrict__ fw)
{
    const int br = blockIdx.x >> 6;
    const int i  = blockIdx.x & 63;
    const float* W    = (br == 0) ? Wc : (br == 1) ? Wh : Ww;
    const float* vecT = (br == 0) ? cvecT : (br == 1) ? hvecT : wvecT;
    float* out        = (br == 0) ? fc : (br == 1) ? fh : fw;

    __shared__ float Wt[64][64];    // Wt[j][o]
    __shared__ float vl[64][NB];    // vl[j][b]

    const int t = threadIdx.x;
    {
        const float* Wi = W + (size_t)i * 4096;
#pragma unroll
        for (int r = 0; r < 4; ++r) {
            int f = t + 256 * r;                       // float4 index
            float4 v = *reinterpret_cast<const float4*>(Wi + 4 * f);
            int o = (4 * f) >> 6;
            int j = (4 * f) & 63;
            Wt[j + 0][o] = v.x; Wt[j + 1][o] = v.y; Wt[j + 2][o] = v.z; Wt[j + 3][o] = v.w;
        }
    }
    {
#pragma unroll
        for (int r = 0; r < 8; ++r) {
            int f = t + 256 * r;
            *reinterpret_cast<float4*>(&vl[0][0] + 4 * f) =
                *reinterpret_cast<const float4*>(vecT + 4 * f);
        }
    }
    __syncthreads();

    const int og = t & 7;    // 8 groups of 8 o
    const int bg = t >> 3;   // 32 groups of 4 b
    const int o0 = og * 8;
    const int b0 = bg * 4;

    float acc[4][8];
#pragma unroll
    for (int bb = 0; bb < 4; ++bb)
#pragma unroll
        for (int oo = 0; oo < 8; ++oo) acc[bb][oo] = 0.f;

#pragma unroll 4
    for (int j = 0; j < 64; ++j) {
        float4 vb = *reinterpret_cast<const float4*>(&vl[j][b0]);
        float4 w0 = *reinterpret_cast<const float4*>(&Wt[j][o0]);
        float4 w1 = *reinterpret_cast<const float4*>(&Wt[j][o0 + 4]);
        float vb_[4] = {vb.x, vb.y, vb.z, vb.w};
        float wv_[8] = {w0.x, w0.y, w0.z, w0.w, w1.x, w1.y, w1.z, w1.w};
#pragma unroll
        for (int bb = 0; bb < 4; ++bb)
#pragma unroll
            for (int oo = 0; oo < 8; ++oo)
                acc[bb][oo] += vb_[bb] * wv_[oo];
    }

#pragma unroll
    for (int bb = 0; bb < 4; ++bb) {
        float4 r0, r1;
        r0.x = 1.f / (1.f + __expf(-acc[bb][0]));
        r0.y = 1.f / (1.f + __expf(-acc[bb][1]));
        r0.z = 1.f / (1.f + __expf(-acc[bb][2]));
        r0.w = 1.f / (1.f + __expf(-acc[bb][3]));
        r1.x = 1.f / (1.f + __expf(-acc[bb][4]));
        r1.y = 1.f / (1.f + __expf(-acc[bb][5]));
        r1.z = 1.f / (1.f + __expf(-acc[bb][6]));
        r1.w = 1.f / (1.f + __expf(-acc[bb][7]));
        size_t base = ((size_t)(b0 + bb) * 64 + i) * 64 + o0;  // [b][i][o]
        *reinterpret_cast<float4*>(&out[base])     = r0;
        *reinterpret_cast<float4*>(&out[base + 4]) = r1;
    }
}

// ---------------------------------------------------------------------------
// Kernel 3: LR[b,c,p,q] = sum_i fc[b,i,c] * fh[b,i,p] * fw[b,i,q].
// Grid 512 = (b, pblk of 16 p). Per p: 64x64x64 GEMM with on-the-fly B.
// 8c x 4q register tile keeps LDS b128 traffic under the FMA cycle count.
// ---------------------------------------------------------------------------
__global__ __launch_bounds__(256) void recon_kernel(const float* __restrict__ fc,
                                                    const float* __restrict__ fh,
                                                    const float* __restrict__ fw,
                                                    float* __restrict__ out)
{
    const int blk  = blockIdx.x;
    const int b    = blk >> 2;
    const int pblk = blk & 3;
    const int t    = threadIdx.x;

    __shared__ float fcl[64 * 64];   // [i][c]
    __shared__ float fwl[64 * 64];   // [i][q]
    __shared__ float fhl[64 * 16];   // [i][p-local]

    const float* fcb = fc + (size_t)b * 4096;
    const float* fwb = fw + (size_t)b * 4096;
    const float* fhb = fh + (size_t)b * 4096;

#pragma unroll
    for (int r = 0; r < 4; ++r) {
        int f = t + 256 * r;
        *reinterpret_cast<float4*>(&fcl[4 * f]) = *reinterpret_cast<const float4*>(fcb + 4 * f);
        *reinterpret_cast<float4*>(&fwl[4 * f]) = *reinterpret_cast<const float4*>(fwb + 4 * f);
    }
    {
        int i = t >> 2, col = (t & 3) * 4;
        *reinterpret_cast<float4*>(&fhl[i * 16 + col]) =
            *reinterpret_cast<const float4*>(fhb + i * 64 + pblk * 16 + col);
    }
    __syncthreads();

    const int pp = t >> 7;         // 0..1
    const int cg = (t >> 4) & 7;   // 8 groups of 8 c
    const int qg = t & 15;         // 16 groups of 4 q
    const int c0 = cg * 8, q0 = qg * 4;

    for (int pc = 0; pc < 8; ++pc) {
        const int p = pc * 2 + pp;  // local p 0..15
        float acc[8][4];
#pragma unroll
        for (int cc = 0; cc < 8; ++cc)
#pragma unroll
            for (int m = 0; m < 4; ++m) acc[cc][m] = 0.f;

#pragma unroll 4
        for (int i = 0; i < 64; ++i) {
            float4 a0 = *reinterpret_cast<const float4*>(&fcl[i * 64 + c0]);
            float4 a1 = *reinterpret_cast<const float4*>(&fcl[i * 64 + c0 + 4]);
            float4 wq = *reinterpret_cast<const float4*>(&fwl[i * 64 + q0]);
            float hp  = fhl[i * 16 + p];
            float g0 = hp * wq.x, g1 = hp * wq.y, g2 = hp * wq.z, g3 = hp * wq.w;
            float a_[8] = {a0.x, a0.y, a0.z, a0.w, a1.x, a1.y, a1.z, a1.w};
#pragma unroll
            for (int cc = 0; cc < 8; ++cc) {
                acc[cc][0] += a_[cc] * g0;
                acc[cc][1] += a_[cc] * g1;
                acc[cc][2] += a_[cc] * g2;
                acc[cc][3] += a_[cc] * g3;
            }
        }

        size_t base = (((size_t)b * 64 + c0) * 64 + pblk * 16 + p) * 64 + q0;
#pragma unroll
        for (int cc = 0; cc < 8; ++cc) {
            float4 r;
            r.x = acc[cc][0]; r.y = acc[cc][1]; r.z = acc[cc][2]; r.w = acc[cc][3];
            *reinterpret_cast<float4*>(&out[base + (size_t)cc * 4096]) = r;
        }
    }
}

// ---------------------------------------------------------------------------
extern "C" void kernel_launch(void* const* d_in, const int* in_sizes, int n_in,
                              void* d_out, int out_size, void* d_ws, size_t ws_size,
                              hipStream_t stream) {
    (void)in_sizes; (void)n_in; (void)out_size; (void)ws_size;
    const float* x  = (const float*)d_in[0];
    const float* Wc = (const float*)d_in[1];
    const float* Wh = (const float*)d_in[2];
    const float* Ww = (const float*)d_in[3];
    float* out = (float*)d_out;

    float* ws    = (float*)d_ws;
    float* cvecT = ws;               // 64*128
    float* hvecT = ws + 8192;        // 64*128 (per-w descriptor)
    float* wvecT = ws + 16384;       // 64*128 (per-h descriptor)
    float* fc    = ws + 24576;       // 128*64*64
    float* fh    = fc + 524288;
    float* fw    = fh + 524288;

    // h/w descriptors are accumulated with atomics -> must be zeroed each call
    hipMemsetAsync(hvecT, 0, 2 * 8192 * sizeof(float), stream);

    pool_kernel<<<512, 256, 0, stream>>>(x, cvecT, hvecT, wvecT);
    fvec_kernel<<<192, 256, 0, stream>>>(Wc, Wh, Ww, cvecT, hvecT, wvecT, fc, fh, fw);
    recon_kernel<<<512, 256, 0, stream>>>(fc, fh, fw, out);
}

// Round 2
// 77.661 us; speedup vs baseline: 1.4250x; 1.4250x over previous
//
#include <hip/hip_runtime.h>
#include <hip/hip_bf16.h>

// B=128, D=64.
//   c_vec[b,c] = mean_{h,w} x[b,c,h,w]    (cvec)
//   h_vec[b,w] = mean_{c,h} x[b,c,h,w]    (hv)
//   w_vec[b,h] = mean_{c,w} x[b,c,h,w]    (wv)
//   f*[b,i,o] = sigmoid(sum_j W*[i,o,j] * vec[b,j])
//   LR[b,c,p,q] = sum_i fc[b,i,c]*fh[b,i,p]*fw[b,i,q]
// Stage 3 as MFMA: per (b,p): C[c,q] = sum_i A[c,i]*B[i,q], A=fc^T, B[i,q]=fh[i,p]*fw[i,q].

#define NB 128

typedef __attribute__((ext_vector_type(8))) short bf16x8;
typedef __attribute__((ext_vector_type(4))) float f32x4;

__device__ __forceinline__ float bf2f(short s) {
    return __uint_as_float(((unsigned)(unsigned short)s) << 16);
}
// RNE pack of two f32 -> packed bf16x2 (lo=a, hi=b)
__device__ __forceinline__ unsigned packbf2(float a, float b) {
    unsigned ua = __float_as_uint(a); ua += 0x7fffu + ((ua >> 16) & 1u);
    unsigned ub = __float_as_uint(b); ub += 0x7fffu + ((ub >> 16) & 1u);
    return (ua >> 16) | (ub & 0xffff0000u);
}
__device__ __forceinline__ unsigned short f2bf(float f) {
    unsigned u = __float_as_uint(f); u += 0x7fffu + ((u >> 16) & 1u);
    return (unsigned short)(u >> 16);
}

// ---------------------------------------------------------------------------
// Kernel 1: fused triple pooling. Grid 512 = (b, cblk of 16 c).
// All cross-lane reduction deferred to after the load loop so loads pipeline.
// Writes cvecT[c][b] (exclusive) and per-cblk partials for h_vec/w_vec
// (no atomics, no memset; fvec sums the 4 partials).
// ---------------------------------------------------------------------------
__global__ __launch_bounds__(256) void pool_kernel(const float* __restrict__ x,
                                                   float* __restrict__ cvecT,    // [64][128]
                                                   float* __restrict__ hv_part,  // [4][64][128] per-w (ref h_vec)
                                                   float* __restrict__ wv_part)  // [4][64][128] per-h (ref w_vec)
{
    const int blk  = blockIdx.x;
    const int b    = blk >> 2;
    const int cblk = blk & 3;
    const int t    = threadIdx.x;
    const int wv   = t >> 6;
    const int l    = t & 63;
    const int lg   = l >> 4;
    const int lw   = l & 15;

    __shared__ float cpart[16][4];
    __shared__ float hsum_l[64];    // per-h sums -> w_vec
    __shared__ float wpart[4][64];  // per-w per-wave partial -> h_vec

    const float* xb = x + (size_t)b * 262144 + (size_t)cblk * 65536;

    float cs[16];
    float acc_h[4] = {0.f, 0.f, 0.f, 0.f};
    float acc_w[4] = {0.f, 0.f, 0.f, 0.f};

#pragma unroll
    for (int cc = 0; cc < 16; ++cc) {
        const float* xc = xb + cc * 4096 + wv * 1024 + 4 * l;
        float sc = 0.f;
#pragma unroll
        for (int k = 0; k < 4; ++k) {
            float4 v = *reinterpret_cast<const float4*>(xc + k * 256);
            float s = (v.x + v.y) + (v.z + v.w);
            sc += s;
            acc_h[k] += s;
            acc_w[0] += v.x; acc_w[1] += v.y; acc_w[2] += v.z; acc_w[3] += v.w;
        }
        cs[cc] = sc;
    }

    // tail: per-c full-wave reductions (now off the load critical path)
#pragma unroll
    for (int cc = 0; cc < 16; ++cc) {
        float v = cs[cc];
#pragma unroll
        for (int off = 32; off >= 1; off >>= 1) v += __shfl_xor(v, off, 64);
        if (l == 0) cpart[cc][wv] = v;
    }
    // per-h: reduce acc_h over the 16 lanes sharing lg
#pragma unroll
    for (int k = 0; k < 4; ++k) {
        float v = acc_h[k];
        v += __shfl_xor(v, 1, 64);
        v += __shfl_xor(v, 2, 64);
        v += __shfl_xor(v, 4, 64);
        v += __shfl_xor(v, 8, 64);
        if (lw == 0) hsum_l[wv * 16 + k * 4 + lg] = v;
    }
    // per-w: reduce acc_w over the 4 lanes sharing lw
#pragma unroll
    for (int m = 0; m < 4; ++m) {
        float v = acc_w[m];
        v += __shfl_xor(v, 16, 64);
        v += __shfl_xor(v, 32, 64);
        if (lg == 0) wpart[wv][lw * 4 + m] = v;
    }
    __syncthreads();

    const float scale = 1.f / 4096.f;
    if (t < 16) {
        float s = cpart[t][0] + cpart[t][1] + cpart[t][2] + cpart[t][3];
        cvecT[(cblk * 16 + t) * NB + b] = s * scale;
    }
    if (t < 64) {
        wv_part[(cblk * 64 + t) * NB + b] = hsum_l[t] * scale;               // per-h
        float ws_ = wpart[0][t] + wpart[1][t] + wpart[2][t] + wpart[3][t];   // per-w
        hv_part[(cblk * 64 + t) * NB + b] = ws_ * scale;
    }
}

// ---------------------------------------------------------------------------
// Kernel 2: f*[b,i,o] = sigmoid(sum_j W[i,o,j]*vec[b,j]); writes TRANSPOSED
// bf16 fT[b][o][i] (what recon's MFMA fragments want). Grid 192 = (branch, i).
// For h/w branches the pool partials (4x) are summed during vec staging.
// ---------------------------------------------------------------------------
__global__ __launch_bounds__(256) void fvec_kernel(const float* __restrict__ Wc,
                                                   const float* __restrict__ Wh,
                                                   const float* __restrict__ Ww,
                                                   const float* __restrict__ cvecT,
                                                   const float* __restrict__ hv_part,
                                                   const float* __restrict__ wv_part,
                                                   unsigned short* __restrict__ fcT,
                                                   unsigned short* __restrict__ fhT,
                                                   unsigned short* __restrict__ fwT)
{
    const int br = blockIdx.x >> 6;
    const int i  = blockIdx.x & 63;
    const float* W = (br == 0) ? Wc : (br == 1) ? Wh : Ww;
    const float* V = (br == 0) ? cvecT : (br == 1) ? hv_part : wv_part;
    unsigned short* outT = (br == 0) ? fcT : (br == 1) ? fhT : fwT;

    __shared__ float Wt[64][64];     // Wt[j][o]
    __shared__ float vl[64 * NB];    // vl[j][b]

    const int t = threadIdx.x;
    {
        const float* Wi = W + (size_t)i * 4096;
#pragma unroll
        for (int r = 0; r < 4; ++r) {
            int f = t + 256 * r;
            float4 v = reinterpret_cast<const float4*>(Wi)[f];
            int o = (4 * f) >> 6;
            int j = (4 * f) & 63;
            Wt[j + 0][o] = v.x; Wt[j + 1][o] = v.y; Wt[j + 2][o] = v.z; Wt[j + 3][o] = v.w;
        }
    }
#pragma unroll
    for (int r = 0; r < 8; ++r) {
        int f = t + 256 * r;
        float4 v = reinterpret_cast<const float4*>(V)[f];
        if (br != 0) {
            float4 v1 = reinterpret_cast<const float4*>(V + 8192)[f];
            float4 v2 = reinterpret_cast<const float4*>(V + 16384)[f];
            float4 v3 = reinterpret_cast<const float4*>(V + 24576)[f];
            v.x += (v1.x + v2.x) + v3.x;
            v.y += (v1.y + v2.y) + v3.y;
            v.z += (v1.z + v2.z) + v3.z;
            v.w += (v1.w + v2.w) + v3.w;
        }
        reinterpret_cast<float4*>(vl)[f] = v;
    }
    __syncthreads();

    const int og = t & 7;
    const int bg = t >> 3;
    const int o0 = og * 8;
    const int b0 = bg * 4;

    float acc[4][8];
#pragma unroll
    for (int bb = 0; bb < 4; ++bb)
#pragma unroll
        for (int oo = 0; oo < 8; ++oo) acc[bb][oo] = 0.f;

#pragma unroll 4
    for (int j = 0; j < 64; ++j) {
        float4 vb = *reinterpret_cast<const float4*>(&vl[j * NB + b0]);
        float4 w0 = *reinterpret_cast<const float4*>(&Wt[j][o0]);
        float4 w1 = *reinterpret_cast<const float4*>(&Wt[j][o0 + 4]);
        float vb_[4] = {vb.x, vb.y, vb.z, vb.w};
        float wv_[8] = {w0.x, w0.y, w0.z, w0.w, w1.x, w1.y, w1.z, w1.w};
#pragma unroll
        for (int bb = 0; bb < 4; ++bb)
#pragma unroll
            for (int oo = 0; oo < 8; ++oo)
                acc[bb][oo] += vb_[bb] * wv_[oo];
    }

#pragma unroll
    for (int bb = 0; bb < 4; ++bb)
#pragma unroll
        for (int oo = 0; oo < 8; ++oo) {
            float sg = 1.f / (1.f + __expf(-acc[bb][oo]));
            outT[((size_t)(b0 + bb) * 64 + (o0 + oo)) * 64 + i] = f2bf(sg);
        }
}

// ---------------------------------------------------------------------------
// Kernel 3: MFMA recon. Grid 512 = (b, pblk of 16 p), 4 waves, wave w owns
// p = w*4+pp. LDS tiles padded to 72 elems/row (bank-conflict-free b128).
// A-frag: lane holds fcT[ct*16+(l&15)][k0..k0+7], k0 = kb*32+(l>>4)*8.
// B-frag built in-register: bf16(fh[k,p]*fw[k,q]). C/D: col=l&15, row=(l>>4)*4+r.
// ---------------------------------------------------------------------------
__global__ __launch_bounds__(256) void recon_kernel(const unsigned short* __restrict__ fcT,
                                                    const unsigned short* __restrict__ fhT,
                                                    const unsigned short* __restrict__ fwT,
                                                    float* __restrict__ out)
{
    const int blk  = blockIdx.x;
    const int b    = blk >> 2;
    const int pblk = blk & 3;
    const int t    = threadIdx.x;
    const int w    = t >> 6;
    const int l    = t & 63;
    const int lr   = l & 15;
    const int lg4  = l >> 4;

    __shared__ __align__(16) unsigned short fcl[64 * 72];
    __shared__ __align__(16) unsigned short fwl[64 * 72];
    __shared__ __align__(16) unsigned short fhl[16 * 72];

    const unsigned short* fcb = fcT + (size_t)b * 4096;
    const unsigned short* fwb = fwT + (size_t)b * 4096;
    const unsigned short* fhb = fhT + (size_t)b * 4096 + pblk * 1024;

#pragma unroll
    for (int r = 0; r < 2; ++r) {
        int f = t + 256 * r;
        *reinterpret_cast<int4*>(&fcl[(f >> 3) * 72 + (f & 7) * 8]) =
            reinterpret_cast<const int4*>(fcb)[f];
        *reinterpret_cast<int4*>(&fwl[(f >> 3) * 72 + (f & 7) * 8]) =
            reinterpret_cast<const int4*>(fwb)[f];
    }
    if (t < 128) {
        *reinterpret_cast<int4*>(&fhl[(t >> 3) * 72 + (t & 7) * 8]) =
            reinterpret_cast<const int4*>(fhb)[t];
    }
    __syncthreads();

    bf16x8 afr[4][2], wfr[4][2];
#pragma unroll
    for (int ct = 0; ct < 4; ++ct)
#pragma unroll
        for (int kb = 0; kb < 2; ++kb) {
            afr[ct][kb] = *reinterpret_cast<const bf16x8*>(
                &fcl[(ct * 16 + lr) * 72 + kb * 32 + lg4 * 8]);
            wfr[ct][kb] = *reinterpret_cast<const bf16x8*>(
                &fwl[(ct * 16 + lr) * 72 + kb * 32 + lg4 * 8]);
        }

    for (int pp = 0; pp < 4; ++pp) {
        const int p = w * 4 + pp;   // local p within pblk
        float hv[16];
#pragma unroll
        for (int kb = 0; kb < 2; ++kb) {
            bf16x8 hf = *reinterpret_cast<const bf16x8*>(
                &fhl[p * 72 + kb * 32 + lg4 * 8]);   // broadcast within 16-lane group
#pragma unroll
            for (int j = 0; j < 8; ++j) hv[kb * 8 + j] = bf2f(hf[j]);
        }
#pragma unroll
        for (int qt = 0; qt < 4; ++qt) {
            bf16x8 bfr0, bfr1;
            {
                union { unsigned u[4]; bf16x8 v; } bu;
#pragma unroll
                for (int jj = 0; jj < 4; ++jj) {
                    float p0 = hv[2 * jj]     * bf2f(wfr[qt][0][2 * jj]);
                    float p1 = hv[2 * jj + 1] * bf2f(wfr[qt][0][2 * jj + 1]);
                    bu.u[jj] = packbf2(p0, p1);
                }
                bfr0 = bu.v;
            }
            {
                union { unsigned u[4]; bf16x8 v; } bu;
#pragma unroll
                for (int jj = 0; jj < 4; ++jj) {
                    float p0 = hv[8 + 2 * jj]     * bf2f(wfr[qt][1][2 * jj]);
                    float p1 = hv[8 + 2 * jj + 1] * bf2f(wfr[qt][1][2 * jj + 1]);
                    bu.u[jj] = packbf2(p0, p1);
                }
                bfr1 = bu.v;
            }
#pragma unroll
            for (int ct = 0; ct < 4; ++ct) {
                f32x4 acc = {0.f, 0.f, 0.f, 0.f};
                acc = __builtin_amdgcn_mfma_f32_16x16x32_bf16(afr[ct][0], bfr0, acc, 0, 0, 0);
                acc = __builtin_amdgcn_mfma_f32_16x16x32_bf16(afr[ct][1], bfr1, acc, 0, 0, 0);
                float* ob = out + (((size_t)b * 64 + ct * 16 + lg4 * 4) * 64
                                   + (pblk * 16 + p)) * 64 + qt * 16 + lr;
#pragma unroll
                for (int r = 0; r < 4; ++r) ob[(size_t)r * 4096] = acc[r];
            }
        }
    }
}

// ---------------------------------------------------------------------------
extern "C" void kernel_launch(void* const* d_in, const int* in_sizes, int n_in,
                              void* d_out, int out_size, void* d_ws, size_t ws_size,
                              hipStream_t stream) {
    (void)in_sizes; (void)n_in; (void)out_size; (void)ws_size;
    const float* x  = (const float*)d_in[0];
    const float* Wc = (const float*)d_in[1];
    const float* Wh = (const float*)d_in[2];
    const float* Ww = (const float*)d_in[3];
    float* out = (float*)d_out;

    float* ws      = (float*)d_ws;
    float* cvecT   = ws;                 // 64*128 f32
    float* hv_part = ws + 8192;          // 4*64*128 f32
    float* wv_part = ws + 40960;         // 4*64*128 f32
    unsigned short* fcT = (unsigned short*)(ws + 73728);  // 128*64*64 bf16 each
    unsigned short* fhT = fcT + 524288;
    unsigned short* fwT = fhT + 524288;

    pool_kernel<<<512, 256, 0, stream>>>(x, cvecT, hv_part, wv_part);
    fvec_kernel<<<192, 256, 0, stream>>>(Wc, Wh, Ww, cvecT, hv_part, wv_part, fcT, fhT, fwT);
    recon_kernel<<<512, 256, 0, stream>>>(fcT, fhT, fwT, out);
}

// Round 3
// 70.859 us; speedup vs baseline: 1.5618x; 1.0960x over previous
//
#include <hip/hip_runtime.h>
#include <hip/hip_bf16.h>

// B=128, D=64.
//   c_vec[b,c] = mean_{h,w} x[b,c,h,w]
//   h_vec[b,w] = mean_{c,h} x[b,c,h,w]
//   w_vec[b,h] = mean_{c,w} x[b,c,h,w]
//   f*[b,i,o] = sigmoid(sum_j W*[i,o,j] * vec[b,j])
//   LR[b,c,p,q] = sum_i fc[b,i,c]*fh[b,i,p]*fw[b,i,q]
// Stage 3 as MFMA: per (b,p): C[c,q] = sum_i A[c,i]*B[i,q], A=fc^T, B[i,q]=fh[i,p]*fw[i,q].
// Epilogue: per-wave LDS bounce -> float4 stores in 256B-contiguous c-rows.

#define NB 128

typedef __attribute__((ext_vector_type(8))) short bf16x8;
typedef __attribute__((ext_vector_type(4))) float f32x4;

__device__ __forceinline__ float bf2f(short s) {
    return __uint_as_float(((unsigned)(unsigned short)s) << 16);
}
__device__ __forceinline__ unsigned packbf2(float a, float b) {
    unsigned ua = __float_as_uint(a); ua += 0x7fffu + ((ua >> 16) & 1u);
    unsigned ub = __float_as_uint(b); ub += 0x7fffu + ((ub >> 16) & 1u);
    return (ua >> 16) | (ub & 0xffff0000u);
}
__device__ __forceinline__ unsigned short f2bf(float f) {
    unsigned u = __float_as_uint(f); u += 0x7fffu + ((u >> 16) & 1u);
    return (unsigned short)(u >> 16);
}

// ---------------------------------------------------------------------------
// Kernel 1: fused triple pooling. Grid 1024 = (b, cblk of 8 c) -> 16 waves/CU.
// Cross-lane reductions deferred out of the load loop. No atomics: per-cblk
// partials for h/w vecs; fvec sums the 8 partials during staging.
// ---------------------------------------------------------------------------
__global__ __launch_bounds__(256) void pool_kernel(const float* __restrict__ x,
                                                   float* __restrict__ cvecT,    // [64][128]
                                                   float* __restrict__ hv_part,  // [8][64][128] per-w (ref h_vec)
                                                   float* __restrict__ wv_part)  // [8][64][128] per-h (ref w_vec)
{
    const int blk  = blockIdx.x;
    const int b    = blk >> 3;
    const int cblk = blk & 7;
    const int t    = threadIdx.x;
    const int wv   = t >> 6;
    const int l    = t & 63;
    const int lg   = l >> 4;
    const int lw   = l & 15;

    __shared__ float cpart[8][4];
    __shared__ float hsum_l[64];    // per-h sums -> w_vec
    __shared__ float wpart[4][64];  // per-w per-wave partial -> h_vec

    const float* xb = x + (size_t)b * 262144 + (size_t)cblk * 32768;

    float cs[8];
    float acc_h[4] = {0.f, 0.f, 0.f, 0.f};
    float acc_w[4] = {0.f, 0.f, 0.f, 0.f};

#pragma unroll
    for (int cc = 0; cc < 8; ++cc) {
        const float* xc = xb + cc * 4096 + wv * 1024 + 4 * l;
        float sc = 0.f;
#pragma unroll
        for (int k = 0; k < 4; ++k) {
            float4 v = *reinterpret_cast<const float4*>(xc + k * 256);
            float s = (v.x + v.y) + (v.z + v.w);
            sc += s;
            acc_h[k] += s;
            acc_w[0] += v.x; acc_w[1] += v.y; acc_w[2] += v.z; acc_w[3] += v.w;
        }
        cs[cc] = sc;
    }

#pragma unroll
    for (int cc = 0; cc < 8; ++cc) {
        float v = cs[cc];
#pragma unroll
        for (int off = 32; off >= 1; off >>= 1) v += __shfl_xor(v, off, 64);
        if (l == 0) cpart[cc][wv] = v;
    }
#pragma unroll
    for (int k = 0; k < 4; ++k) {
        float v = acc_h[k];
        v += __shfl_xor(v, 1, 64);
        v += __shfl_xor(v, 2, 64);
        v += __shfl_xor(v, 4, 64);
        v += __shfl_xor(v, 8, 64);
        if (lw == 0) hsum_l[wv * 16 + k * 4 + lg] = v;
    }
#pragma unroll
    for (int m = 0; m < 4; ++m) {
        float v = acc_w[m];
        v += __shfl_xor(v, 16, 64);
        v += __shfl_xor(v, 32, 64);
        if (lg == 0) wpart[wv][lw * 4 + m] = v;
    }
    __syncthreads();

    const float scale = 1.f / 4096.f;
    if (t < 8) {
        float s = cpart[t][0] + cpart[t][1] + cpart[t][2] + cpart[t][3];
        cvecT[(cblk * 8 + t) * NB + b] = s * scale;
    }
    if (t < 64) {
        wv_part[(cblk * 64 + t) * NB + b] = hsum_l[t] * scale;               // per-h
        float ws_ = wpart[0][t] + wpart[1][t] + wpart[2][t] + wpart[3][t];   // per-w
        hv_part[(cblk * 64 + t) * NB + b] = ws_ * scale;
    }
}

// ---------------------------------------------------------------------------
// Kernel 2: f*[b,i,o] = sigmoid(sum_j W[i,o,j]*vec[b,j]); writes TRANSPOSED
// bf16 fT[b][o][i]. Grid 192 = (branch, i). h/w branches sum 8 pool partials.
// ---------------------------------------------------------------------------
__global__ __launch_bounds__(256) void fvec_kernel(const float* __restrict__ Wc,
                                                   const float* __restrict__ Wh,
                                                   const float* __restrict__ Ww,
                                                   const float* __restrict__ cvecT,
                                                   const float* __restrict__ hv_part,
                                                   const float* __restrict__ wv_part,
                                                   unsigned short* __restrict__ fcT,
                                                   unsigned short* __restrict__ fhT,
                                                   unsigned short* __restrict__ fwT)
{
    const int br = blockIdx.x >> 6;
    const int i  = blockIdx.x & 63;
    const float* W = (br == 0) ? Wc : (br == 1) ? Wh : Ww;
    const float* V = (br == 0) ? cvecT : (br == 1) ? hv_part : wv_part;
    unsigned short* outT = (br == 0) ? fcT : (br == 1) ? fhT : fwT;

    __shared__ float Wt[64][64];     // Wt[j][o]
    __shared__ float vl[64 * NB];    // vl[j][b]

    const int t = threadIdx.x;
    {
        const float* Wi = W + (size_t)i * 4096;
#pragma unroll
        for (int r = 0; r < 4; ++r) {
            int f = t + 256 * r;
            float4 v = reinterpret_cast<const float4*>(Wi)[f];
            int o = (4 * f) >> 6;
            int j = (4 * f) & 63;
            Wt[j + 0][o] = v.x; Wt[j + 1][o] = v.y; Wt[j + 2][o] = v.z; Wt[j + 3][o] = v.w;
        }
    }
#pragma unroll
    for (int r = 0; r < 8; ++r) {
        int f = t + 256 * r;
        float4 v = reinterpret_cast<const float4*>(V)[f];
        if (br != 0) {
#pragma unroll
            for (int k = 1; k < 8; ++k) {
                float4 u = reinterpret_cast<const float4*>(V + 8192 * k)[f];
                v.x += u.x; v.y += u.y; v.z += u.z; v.w += u.w;
            }
        }
        reinterpret_cast<float4*>(vl)[f] = v;
    }
    __syncthreads();

    const int og = t & 7;
    const int bg = t >> 3;
    const int o0 = og * 8;
    const int b0 = bg * 4;

    float acc[4][8];
#pragma unroll
    for (int bb = 0; bb < 4; ++bb)
#pragma unroll
        for (int oo = 0; oo < 8; ++oo) acc[bb][oo] = 0.f;

#pragma unroll 4
    for (int j = 0; j < 64; ++j) {
        float4 vb = *reinterpret_cast<const float4*>(&vl[j * NB + b0]);
        float4 w0 = *reinterpret_cast<const float4*>(&Wt[j][o0]);
        float4 w1 = *reinterpret_cast<const float4*>(&Wt[j][o0 + 4]);
        float vb_[4] = {vb.x, vb.y, vb.z, vb.w};
        float wv_[8] = {w0.x, w0.y, w0.z, w0.w, w1.x, w1.y, w1.z, w1.w};
#pragma unroll
        for (int bb = 0; bb < 4; ++bb)
#pragma unroll
            for (int oo = 0; oo < 8; ++oo)
                acc[bb][oo] += vb_[bb] * wv_[oo];
    }

#pragma unroll
    for (int bb = 0; bb < 4; ++bb)
#pragma unroll
        for (int oo = 0; oo < 8; ++oo) {
            float sg = 1.f / (1.f + __expf(-acc[bb][oo]));
            outT[((size_t)(b0 + bb) * 64 + (o0 + oo)) * 64 + i] = f2bf(sg);
        }
}

// ---------------------------------------------------------------------------
// Kernel 3: MFMA recon. Grid 512 = (b, pblk of 16 p), 4 waves, wave w owns
// p = w*4+pp. Frags from padded LDS (72-pitch). Per (pp): build all 4 B-frag
// pairs, then per ct: 8 MFMA -> per-wave LDS bounce (XOR-swizzled cols) ->
// float4 stores covering 256B-contiguous c-rows (4 rows / 1KB per instr).
// ---------------------------------------------------------------------------
__global__ __launch_bounds__(256) void recon_kernel(const unsigned short* __restrict__ fcT,
                                                    const unsigned short* __restrict__ fhT,
                                                    const unsigned short* __restrict__ fwT,
                                                    float* __restrict__ out)
{
    const int blk  = blockIdx.x;
    const int b    = blk >> 2;
    const int pblk = blk & 3;
    const int t    = threadIdx.x;
    const int w    = t >> 6;
    const int l    = t & 63;
    const int lr   = l & 15;
    const int lg4  = l >> 4;

    __shared__ __align__(16) unsigned short fcl[64 * 72];
    __shared__ __align__(16) unsigned short fwl[64 * 72];
    __shared__ __align__(16) unsigned short fhl[16 * 72];
    __shared__ __align__(16) float bounce[4][16 * 72];

    const unsigned short* fcb = fcT + (size_t)b * 4096;
    const unsigned short* fwb = fwT + (size_t)b * 4096;
    const unsigned short* fhb = fhT + (size_t)b * 4096 + pblk * 1024;

#pragma unroll
    for (int r = 0; r < 2; ++r) {
        int f = t + 256 * r;
        *reinterpret_cast<int4*>(&fcl[(f >> 3) * 72 + (f & 7) * 8]) =
            reinterpret_cast<const int4*>(fcb)[f];
        *reinterpret_cast<int4*>(&fwl[(f >> 3) * 72 + (f & 7) * 8]) =
            reinterpret_cast<const int4*>(fwb)[f];
    }
    if (t < 128) {
        *reinterpret_cast<int4*>(&fhl[(t >> 3) * 72 + (t & 7) * 8]) =
            reinterpret_cast<const int4*>(fhb)[t];
    }
    __syncthreads();

    bf16x8 afr[4][2], wfr[4][2];
#pragma unroll
    for (int ct = 0; ct < 4; ++ct)
#pragma unroll
        for (int kb = 0; kb < 2; ++kb) {
            afr[ct][kb] = *reinterpret_cast<const bf16x8*>(
                &fcl[(ct * 16 + lr) * 72 + kb * 32 + lg4 * 8]);
            wfr[ct][kb] = *reinterpret_cast<const bf16x8*>(
                &fwl[(ct * 16 + lr) * 72 + kb * 32 + lg4 * 8]);
        }

    float* bw = &bounce[w][0];

    for (int pp = 0; pp < 4; ++pp) {
        const int p = w * 4 + pp;   // local p within pblk
        float hv[16];
#pragma unroll
        for (int kb = 0; kb < 2; ++kb) {
            bf16x8 hf = *reinterpret_cast<const bf16x8*>(
                &fhl[p * 72 + kb * 32 + lg4 * 8]);   // broadcast within 16-lane group
#pragma unroll
            for (int j = 0; j < 8; ++j) hv[kb * 8 + j] = bf2f(hf[j]);
        }
        // build all 4 B-fragment pairs for this p
        bf16x8 b0s[4], b1s[4];
#pragma unroll
        for (int qt = 0; qt < 4; ++qt) {
            union { unsigned u[4]; bf16x8 v; } bu0, bu1;
#pragma unroll
            for (int jj = 0; jj < 4; ++jj) {
                float p0 = hv[2 * jj]     * bf2f(wfr[qt][0][2 * jj]);
                float p1 = hv[2 * jj + 1] * bf2f(wfr[qt][0][2 * jj + 1]);
                bu0.u[jj] = packbf2(p0, p1);
                float p2 = hv[8 + 2 * jj]     * bf2f(wfr[qt][1][2 * jj]);
                float p3 = hv[8 + 2 * jj + 1] * bf2f(wfr[qt][1][2 * jj + 1]);
                bu1.u[jj] = packbf2(p2, p3);
            }
            b0s[qt] = bu0.v; b1s[qt] = bu1.v;
        }

#pragma unroll
        for (int ct = 0; ct < 4; ++ct) {
            // 8 MFMA: full (16c x 64q) strip for this (p, ct)
            f32x4 acc[4];
#pragma unroll
            for (int qt = 0; qt < 4; ++qt) {
                f32x4 a = {0.f, 0.f, 0.f, 0.f};
                a = __builtin_amdgcn_mfma_f32_16x16x32_bf16(afr[ct][0], b0s[qt], a, 0, 0, 0);
                a = __builtin_amdgcn_mfma_f32_16x16x32_bf16(afr[ct][1], b1s[qt], a, 0, 0, 0);
                acc[qt] = a;
            }
            // deposit: row = c_local = lg4*4+r, col = q = qt*16+lr, XOR-swizzled
#pragma unroll
            for (int qt = 0; qt < 4; ++qt)
#pragma unroll
                for (int r = 0; r < 4; ++r)
                    bw[(lg4 * 4 + r) * 72 + ((qt * 16 + lr) ^ (lg4 << 4))] = acc[qt][r];
            // read back + contiguous float4 stores (4 c-rows x 256B per instr)
#pragma unroll
            for (int i = 0; i < 4; ++i) {
                int cr = 4 * i + lg4;
                float4 v = *reinterpret_cast<const float4*>(
                    &bw[cr * 72 + ((4 * lr) ^ (i << 4))]);
                *reinterpret_cast<float4*>(
                    out + (((size_t)b * 64 + ct * 16 + cr) * 64 + pblk * 16 + p) * 64 + 4 * lr) = v;
            }
        }
    }
}

// ---------------------------------------------------------------------------
extern "C" void kernel_launch(void* const* d_in, const int* in_sizes, int n_in,
                              void* d_out, int out_size, void* d_ws, size_t ws_size,
                              hipStream_t stream) {
    (void)in_sizes; (void)n_in; (void)out_size; (void)ws_size;
    const float* x  = (const float*)d_in[0];
    const float* Wc = (const float*)d_in[1];
    const float* Wh = (const float*)d_in[2];
    const float* Ww = (const float*)d_in[3];
    float* out = (float*)d_out;

    float* ws      = (float*)d_ws;
    float* cvecT   = ws;                 // 64*128 f32
    float* hv_part = ws + 8192;          // 8*64*128 f32
    float* wv_part = ws + 73728;         // 8*64*128 f32
    unsigned short* fcT = (unsigned short*)(ws + 139264);  // 128*64*64 bf16 each
    unsigned short* fhT = fcT + 524288;
    unsigned short* fwT = fhT + 524288;

    pool_kernel<<<1024, 256, 0, stream>>>(x, cvecT, hv_part, wv_part);
    fvec_kernel<<<192, 256, 0, stream>>>(Wc, Wh, Ww, cvecT, hv_part, wv_part, fcT, fhT, fwT);
    recon_kernel<<<512, 256, 0, stream>>>(fcT, fhT, fwT, out);
}